// Round 7
// baseline (231.898 us; speedup 1.0000x reference)
//
#include <hip/hip_runtime.h>
#include <cstdint>
#include <cstddef>

// ---------------------------------------------------------------------------
// SparseMHADecoder: B=2, LQ=4096, LKV=2048, D=1024, H=16, d=64, span=16, stride=2
// R7: software-pipeline gemm_qkv's folded A-f32 path. R6 serialized
//     load->wait->cvt->ds_write->barrier each K-iter (gemm_qkv 37->67us).
//     Now A(k+1) f32 loads issue AFTER barrier#1 and drain at barrier#2,
//     overlapping the 32-MFMA block; cvt+ds_write at iter k+1 finds data
//     in regs. Costs +32 prefetch VGPRs.
// Carried: BK=64, XOR chunk swizzle, XCD swizzle, folded cvt, fp16 numerics.
// ---------------------------------------------------------------------------

typedef _Float16 f16;
typedef _Float16 f16x4 __attribute__((ext_vector_type(4)));
typedef _Float16 f16x8 __attribute__((ext_vector_type(8)));
typedef float v4f __attribute__((ext_vector_type(4)));

#define B_  2
#define LQ_ 4096
#define LKV_ 2048
#define DMODEL 1024
#define NH 16
#define HD 64
#define SPAN 16
#define STRIDE 2

#define NQ_ELEMS  ((size_t)B_ * LQ_ * DMODEL)   // 8388608
#define NKV_ELEMS ((size_t)B_ * LKV_ * DMODEL)  // 4194304

__device__ __forceinline__ void async_copy16(const f16* g, f16* l) {
    __builtin_amdgcn_global_load_lds((const __attribute__((address_space(1))) void*)g,
                                     (__attribute__((address_space(3))) void*)l, 16, 0, 0);
}

// ------------- prep: 4 weight transposes, Wt[n][k] = (f16)W[k][n] ------------
__global__ __launch_bounds__(256)
void transpose_all(const float* __restrict__ W0, const float* __restrict__ W1,
                   const float* __restrict__ W2, const float* __restrict__ W3,
                   f16* __restrict__ T0, f16* __restrict__ T1,
                   f16* __restrict__ T2, f16* __restrict__ T3) {
    const int t = threadIdx.x;
    const int bid = blockIdx.x;             // 1024 = 16x16 tiles x 4 weights
    const int z = bid >> 8, rem = bid & 255;
    const int bx = rem & 15, byy = rem >> 4;
    const float* W;
    f16* Wt;
    switch (z) {
        case 0: W = W0; Wt = T0; break;
        case 1: W = W1; Wt = T1; break;
        case 2: W = W2; Wt = T2; break;
        default: W = W3; Wt = T3; break;
    }
    __shared__ float tile[64][65];
    const int r0 = byy * 64, c0 = bx * 64;
    const int tx = t & 63, ty = t >> 6;     // (64,4)
    for (int i = ty; i < 64; i += 4)
        tile[i][tx] = W[(long)(r0 + i) * DMODEL + c0 + tx];
    __syncthreads();
    for (int i = ty; i < 64; i += 4)
        Wt[(long)(c0 + i) * DMODEL + r0 + tx] = (f16)tile[tx][i];
}

// ---------------- fp16 GEMM body, C[m][n] = sum_k A[m][k]*Bt[n][k] -----------
// 128x128 tile, BK=64, XOR chunk swizzle (R5-verified). A_F32: A read as f32,
// prefetched one K-tile ahead (loads overlap the MFMA block, drained by
// barrier#2), cvt in-register, ds_write to the same swizzled layout.
template <bool OUT_F32, bool A_F32>
__device__ __forceinline__ void gemm_body(const void* __restrict__ Av,
                                          const f16* __restrict__ Bt,
                                          void* __restrict__ Cv,
                                          int rowTile, int colTile) {
    constexpr int K = DMODEL, N = DMODEL;
    __shared__ f16 As[128 * 64];
    __shared__ f16 Bs[128 * 64];
    const int t = threadIdx.x;
    const int lane = t & 63;
    const int w = t >> 6;
    const int wm = w >> 1, wn = w & 1;
    const long rowBase = (long)rowTile * 128;
    const long colBase = (long)colTile * 128;
    const int qrow = lane & 15;
    const int quad = lane >> 4;

    v4f acc[4][4] = {};

    // staging: thread t covers rows srow+32i (i=0..3), LDS chunk schunk holds
    // global chunk schunk^(srow&7) (16B granularity)
    const int srow = t >> 3;          // 0..31
    const int schunk = t & 7;
    const int gchunk = schunk ^ (srow & 7);
    const f16* aptrH = (const f16*)Av + (rowBase + srow) * (long)K + gchunk * 8;
    const float* aptrF = (const float*)Av + (rowBase + srow) * (long)K + gchunk * 8;
    const f16* bptr = Bt + (colBase + srow) * (long)K + gchunk * 8;
    f16* lA = &As[srow * 64 + schunk * 8];
    f16* lB = &Bs[srow * 64 + schunk * 8];

    float4 pf[8];                     // A prefetch: 4 rows x 8 f32
    if (A_F32) {
#pragma unroll
        for (int i = 0; i < 4; ++i) {
            pf[2 * i]     = *(const float4*)(aptrF + i * 32 * (long)K);
            pf[2 * i + 1] = *(const float4*)(aptrF + i * 32 * (long)K + 4);
        }
    }

    for (int k0 = 0; k0 < K; k0 += 64) {
        if (A_F32) {
            // cvt prefetched tile k0 -> LDS (regs already resident)
#pragma unroll
            for (int i = 0; i < 4; ++i) {
                f16x8 o = {(f16)pf[2 * i].x, (f16)pf[2 * i].y,
                           (f16)pf[2 * i].z, (f16)pf[2 * i].w,
                           (f16)pf[2 * i + 1].x, (f16)pf[2 * i + 1].y,
                           (f16)pf[2 * i + 1].z, (f16)pf[2 * i + 1].w};
                *(f16x8*)(lA + i * 2048) = o;
            }
        } else {
#pragma unroll
            for (int i = 0; i < 4; ++i)
                async_copy16(aptrH + k0 + i * 32 * (long)K, lA + i * 2048);
        }
#pragma unroll
        for (int i = 0; i < 4; ++i)
            async_copy16(bptr + k0 + i * 32 * (long)K, lB + i * 2048);
        __syncthreads();  // barrier#1: drains B copies + A ds_writes

        if (A_F32 && k0 + 64 < K) {
            // issue A(k0+64) loads NOW: they fly during the MFMA block and
            // are drained by barrier#2 (compiler's vmcnt(0) there anyway)
#pragma unroll
            for (int i = 0; i < 4; ++i) {
                pf[2 * i]     = *(const float4*)(aptrF + k0 + 64 + i * 32 * (long)K);
                pf[2 * i + 1] = *(const float4*)(aptrF + k0 + 64 + i * 32 * (long)K + 4);
            }
        }
#pragma unroll
        for (int s = 0; s < 2; ++s) {   // two K=32 MFMA steps per BK=64 tile
            const int xk = (s * 4 + quad) ^ (qrow & 7);  // swizzled chunk
            f16x8 af[4], bf[4];
#pragma unroll
            for (int mt = 0; mt < 4; ++mt)
                af[mt] = *(const f16x8*)(&As[(wm * 64 + mt * 16 + qrow) * 64 + xk * 8]);
#pragma unroll
            for (int nt = 0; nt < 4; ++nt)
                bf[nt] = *(const f16x8*)(&Bs[(wn * 64 + nt * 16 + qrow) * 64 + xk * 8]);
#pragma unroll
            for (int mt = 0; mt < 4; ++mt)
#pragma unroll
                for (int nt = 0; nt < 4; ++nt)
                    acc[mt][nt] = __builtin_amdgcn_mfma_f32_16x16x32_f16(
                        af[mt], bf[nt], acc[mt][nt], 0, 0, 0);
        }
        __syncthreads();  // barrier#2: As/Bs reads done; A prefetch drained
    }

    // C/D layout (m89-verified): row = quad*4 + r, col = lane&15
#pragma unroll
    for (int mt = 0; mt < 4; ++mt)
#pragma unroll
        for (int nt = 0; nt < 4; ++nt) {
            const long col = colBase + wn * 64 + nt * 16 + qrow;
#pragma unroll
            for (int r = 0; r < 4; ++r) {
                const long row = rowBase + wm * 64 + mt * 16 + quad * 4 + r;
                if (OUT_F32)
                    ((float*)Cv)[row * (long)N + col] = acc[mt][nt][r];
                else
                    ((f16*)Cv)[row * (long)N + col] = (f16)acc[mt][nt][r];
            }
        }
}

// Fused Q/K/V projection from the ORIGINAL f32 inputs, 1024 blocks,
// XCD-swizzled (R4-verified: FETCH -82%).
__global__ __launch_bounds__(256, 2)
void gemm_qkv(const float* __restrict__ A0, const float* __restrict__ A1,
              const float* __restrict__ A2, const f16* __restrict__ B0,
              const f16* __restrict__ B1, const f16* __restrict__ B2,
              f16* __restrict__ C0, f16* __restrict__ C1, f16* __restrict__ C2) {
    const int id = blockIdx.x;
    const int xcd = id & 7;
    const int g = id >> 3;            // 0..127
    const int ct = g & 7;             // col tile
    int rowIdx = (g >> 3) + xcd * 16; // 0..127
    const float* A;
    const f16* Bt;
    f16* C;
    if (rowIdx < 64) {
        A = A0; Bt = B0; C = C0;
    } else if (rowIdx < 96) {
        A = A1; Bt = B1; C = C1; rowIdx -= 64;
    } else {
        A = A2; Bt = B2; C = C2; rowIdx -= 96;
    }
    gemm_body<false, true>((const void*)A, Bt, (void*)C, rowIdx, ct);
}

__global__ __launch_bounds__(256, 2)
void gemm_out(const f16* __restrict__ A, const f16* __restrict__ Bt,
              float* __restrict__ C) {
    const int id = blockIdx.x;        // 512 blocks
    const int xcd = id & 7;
    const int g = id >> 3;            // 0..63
    const int ct = g & 7;
    const int rowIdx = (g >> 3) + xcd * 8;  // 0..63
    gemm_body<true, false>((const void*)A, Bt, (void*)C, rowIdx, ct);
}

// -------- per-column scores + softmax over the 16 valid query rows ----------
__global__ __launch_bounds__(256)
void attn_scores(const f16* __restrict__ Q, const f16* __restrict__ Km,
                 float* __restrict__ attnw) {
    const int c0 = blockIdx.x * 4, b = blockIdx.y;
    const int t = threadIdx.x;
    __shared__ f16 Qs[24 * 1032];   // rows 0..21 used; 49.5 KB
    __shared__ f16 Ks[4 * 1032];    // 8.25 KB

#pragma unroll
    for (int it = 0; it < 12; ++it) {
        const int ch = t + 256 * it;        // 24 rows x 128 chunks
        const int row = ch >> 7, off = (ch & 127) * 8;
        int qq = 2 * c0 + row;
        if (qq > LQ_ - 1) qq = LQ_ - 1;     // clamp staging; masked in score
        f16x8 x = *(const f16x8*)(Q + (size_t)(b * LQ_ + qq) * DMODEL + off);
        const int h = off >> 6, bb = (off >> 3) & 7;
        *(f16x8*)(&Qs[row * 1032 + h * 64 + ((bb + h) & 7) * 8]) = x;
    }
#pragma unroll
    for (int it = 0; it < 2; ++it) {
        const int ch = t + 256 * it;        // 4 rows x 128 chunks
        const int row = ch >> 7, off = (ch & 127) * 8;
        f16x8 x = *(const f16x8*)(Km + (size_t)(b * LKV_ + c0 + row) * DMODEL + off);
        const int h = off >> 6, bb = (off >> 3) & 7;
        *(f16x8*)(&Ks[row * 1032 + h * 64 + ((bb + h) & 7) * 8]) = x;
    }
    __syncthreads();

    const int h = t >> 4, j = t & 15;
#pragma unroll
    for (int ci = 0; ci < 4; ++ci) {
        const int c = c0 + ci;
        const int q = STRIDE * c + j;
        const int row = 2 * ci + j;
        float a = 0.f;
#pragma unroll
        for (int bb = 0; bb < 8; ++bb) {
            const int off = h * 64 + ((bb + h) & 7) * 8;
            f16x8 qv = *(const f16x8*)(&Qs[row * 1032 + off]);
            f16x8 kv = *(const f16x8*)(&Ks[ci * 1032 + off]);  // wave-broadcast
#pragma unroll
            for (int u = 0; u < 8; ++u) a += (float)qv[u] * (float)kv[u];
        }
        float s = (q < LQ_) ? a : -1e30f;
        float m = s;
#pragma unroll
        for (int o = 1; o < 16; o <<= 1) m = fmaxf(m, __shfl_xor(m, o, 64));
        float p = (q < LQ_) ? __expf(s - m) : 0.f;
        float sum = p;
#pragma unroll
        for (int o = 1; o < 16; o <<= 1) sum += __shfl_xor(sum, o, 64);
        attnw[(size_t)((b * LKV_ + c) * NH + h) * SPAN + j] = p / sum;
    }
}

// ---- ctx[b,q,h,:] = sum_i attn[b, q/2-i, h, (q&1)+2i] * V[b, q/2-i, h, :] ----
__global__ __launch_bounds__(256)
void ctx_gather(const float* __restrict__ attnw, const f16* __restrict__ V,
                f16* __restrict__ ctx) {
    const int q0 = blockIdx.x * 16, b = blockIdx.y;
    const int t = threadIdx.x;
    const int kbase = (q0 >> 1) - 7;
    __shared__ f16 Vs[16 * 1024];     // 32 KB
    __shared__ float A_lds[16 * 256]; // 16 KB

#pragma unroll
    for (int it = 0; it < 8; ++it) {
        const int ch = t + 256 * it;       // 16 rows x 128 chunks
        const int row = ch >> 7, off = (ch & 127) * 8;
        int k = kbase + row;
        k = (k < 0) ? 0 : ((k > LKV_ - 1) ? LKV_ - 1 : k);
        *(f16x8*)(&Vs[row * 1024 + off]) =
            *(const f16x8*)(V + (size_t)(b * LKV_ + k) * DMODEL + off);
    }
#pragma unroll
    for (int it = 0; it < 4; ++it) {
        const int ch = t + 256 * it;       // 16 rows x 64 chunks of 4 f32
        const int row = ch >> 6, off = (ch & 63) * 4;
        int k = kbase + row;
        k = (k < 0) ? 0 : ((k > LKV_ - 1) ? LKV_ - 1 : k);
        *(float4*)(&A_lds[row * 256 + off]) =
            *(const float4*)(attnw + (size_t)(b * LKV_ + k) * 256 + off);
    }
    __syncthreads();

    const int d = t & 63;
    const int hg = t >> 6;
#pragma unroll
    for (int ql = 0; ql < 16; ++ql) {
        const int q = q0 + ql;
        const int j0 = q & 1;
        float acc[4] = {0.f, 0.f, 0.f, 0.f};
#pragma unroll
        for (int i = 0; i < SPAN / STRIDE; ++i) {
            const int kq = (q >> 1) - i;
            if (kq < 0) break;
            const int rr = kq - kbase;
#pragma unroll
            for (int hh = 0; hh < 4; ++hh) {
                const int h = hg * 4 + hh;
                acc[hh] += A_lds[rr * 256 + h * 16 + j0 + 2 * i] *
                           (float)Vs[rr * 1024 + h * 64 + d];
            }
        }
        f16* crow = ctx + (size_t)(b * LQ_ + q) * DMODEL;
#pragma unroll
        for (int hh = 0; hh < 4; ++hh) {
            const int h = hg * 4 + hh;
            crow[h * HD + d] = (f16)acc[hh];
        }
    }
}

// ---------------------------------------------------------------------------
extern "C" void kernel_launch(void* const* d_in, const int* in_sizes, int n_in,
                              void* d_out, int out_size, void* d_ws, size_t ws_size,
                              hipStream_t stream) {
    const float* q  = (const float*)d_in[0];
    const float* k  = (const float*)d_in[1];
    const float* v  = (const float*)d_in[2];
    const float* Wq = (const float*)d_in[3];
    const float* Wk = (const float*)d_in[4];
    const float* Wv = (const float*)d_in[5];
    const float* Wo = (const float*)d_in[6];
    float* out = (float*)d_out;

    const size_t NW = (size_t)DMODEL * DMODEL;

    char* p = (char*)d_ws;
    f16* WqT = (f16*)p; p += NW * 2;
    f16* WkT = (f16*)p; p += NW * 2;
    f16* WvT = (f16*)p; p += NW * 2;
    f16* WoT = (f16*)p; p += NW * 2;
    f16* Qh  = (f16*)p; p += NQ_ELEMS * 2;
    f16* Kh  = (f16*)p; p += NKV_ELEMS * 2;
    f16* Vh  = (f16*)p; p += NKV_ELEMS * 2;
    float* attnw = (float*)p; p += (size_t)B_ * LKV_ * NH * SPAN * 4;
    f16* ctxh = (f16*)p; p += NQ_ELEMS * 2;

    // 1) weight transposes only (q/k/v convert folded into gemm_qkv)
    transpose_all<<<dim3(1024), 256, 0, stream>>>(Wq, Wk, Wv, Wo,
                                                  WqT, WkT, WvT, WoT);

    // 2) Q/K/V projections from f32 inputs, fused + XCD-swizzled + pipelined
    gemm_qkv<<<dim3(1024), 256, 0, stream>>>(q, k, v, WqT, WkT, WvT, Qh, Kh, Vh);

    // 3) per-column masked scores + query-axis softmax
    attn_scores<<<dim3(LKV_ / 4, B_), 256, 0, stream>>>(Qh, Kh, attnw);

    // 4) per-query gather of weighted V
    ctx_gather<<<dim3(LQ_ / 16, B_), 256, 0, stream>>>(attnw, Vh, ctxh);

    // 5) output projection (f32 out), XCD-swizzled
    gemm_out<<<dim3(512), 256, 0, stream>>>(ctxh, WoT, out);
}

// Round 8
// 229.413 us; speedup vs baseline: 1.0108x; 1.0108x over previous
//
#include <hip/hip_runtime.h>
#include <cstdint>
#include <cstddef>

// ---------------------------------------------------------------------------
// SparseMHADecoder: B=2, LQ=4096, LKV=2048, D=1024, H=16, d=64, span=16, stride=2
// R8: REVERT R6/R7's cvt-fold. Evidence: A-through-VGPR staging costs the
//     gemm 30+us (exposed f32-load latency in the 2-barrier K-loop; R6 67us,
//     R7 73us) vs <40us on the all-f16 global_load_lds path (R5), while the
//     separate cvt kernel costs only ~12us. Restored R5 structure with
//     8-elem/thread cvt (16B stores).
// Carried: BK=64 + XOR chunk swizzle (0 bank conflicts), XCD swizzle
// (FETCH -82%), 4-col attn_scores, 16-query ctx_gather, fp16 numerics.
// ---------------------------------------------------------------------------

typedef _Float16 f16;
typedef _Float16 f16x4 __attribute__((ext_vector_type(4)));
typedef _Float16 f16x8 __attribute__((ext_vector_type(8)));
typedef float v4f __attribute__((ext_vector_type(4)));

#define B_  2
#define LQ_ 4096
#define LKV_ 2048
#define DMODEL 1024
#define NH 16
#define HD 64
#define SPAN 16
#define STRIDE 2

#define NQ_ELEMS  ((size_t)B_ * LQ_ * DMODEL)   // 8388608
#define NKV_ELEMS ((size_t)B_ * LKV_ * DMODEL)  // 4194304

__device__ __forceinline__ void async_copy16(const f16* g, f16* l) {
    __builtin_amdgcn_global_load_lds((const __attribute__((address_space(1))) void*)g,
                                     (__attribute__((address_space(3))) void*)l, 16, 0, 0);
}

// ------- fused prep: f32->f16 convert of q,k,v + 4 weight transposes --------
// blocks [0,8192): cvt 8 elems/thread; [8192,9216): transpose 64x64 tiles
__global__ __launch_bounds__(256)
void prep_all(const float* __restrict__ q, const float* __restrict__ k,
              const float* __restrict__ v, f16* __restrict__ qh,
              f16* __restrict__ kh, f16* __restrict__ vh,
              const float* __restrict__ W0, const float* __restrict__ W1,
              const float* __restrict__ W2, const float* __restrict__ W3,
              f16* __restrict__ T0, f16* __restrict__ T1,
              f16* __restrict__ T2, f16* __restrict__ T3) {
    const int t = threadIdx.x;
    if (blockIdx.x < 8192) {
        size_t i = ((size_t)blockIdx.x * 256 + t) * 8;
        const float* src;
        f16* dst;
        if (i < NQ_ELEMS) {
            src = q + i; dst = qh + i;
        } else if (i < NQ_ELEMS + NKV_ELEMS) {
            src = k + (i - NQ_ELEMS); dst = kh + (i - NQ_ELEMS);
        } else {
            src = v + (i - NQ_ELEMS - NKV_ELEMS); dst = vh + (i - NQ_ELEMS - NKV_ELEMS);
        }
        float4 a = *(const float4*)src;
        float4 b = *(const float4*)(src + 4);
        f16x8 o = {(f16)a.x, (f16)a.y, (f16)a.z, (f16)a.w,
                   (f16)b.x, (f16)b.y, (f16)b.z, (f16)b.w};
        *(f16x8*)dst = o;
    } else {
        const int bid = blockIdx.x - 8192;     // 1024 = 4 weights x 16x16 tiles
        const int z = bid >> 8, rem = bid & 255;
        const int bx = rem & 15, byy = rem >> 4;
        const float* W;
        f16* Wt;
        switch (z) {
            case 0: W = W0; Wt = T0; break;
            case 1: W = W1; Wt = T1; break;
            case 2: W = W2; Wt = T2; break;
            default: W = W3; Wt = T3; break;
        }
        __shared__ float tile[64][65];
        const int r0 = byy * 64, c0 = bx * 64;
        const int tx = t & 63, ty = t >> 6;    // (64,4)
        for (int i = ty; i < 64; i += 4)
            tile[i][tx] = W[(long)(r0 + i) * DMODEL + c0 + tx];
        __syncthreads();
        for (int i = ty; i < 64; i += 4)
            Wt[(long)(c0 + i) * DMODEL + r0 + tx] = (f16)tile[tx][i];
    }
}

// ---------------- fp16 GEMM body, C[m][n] = sum_k A[m][k]*Bt[n][k] -----------
// 128x128 tile, BK=64, global_load_lds(16B) with XOR chunk swizzle:
// LDS position p (16B chunks, 8/row) of row r holds global chunk p^(r&7).
// ds_read_b128 covers all 8 bank-groups 2x per phase (2-way = free, m136).
template <bool OUT_F32>
__device__ __forceinline__ void gemm_body(const f16* __restrict__ A,
                                          const f16* __restrict__ Bt,
                                          void* __restrict__ Cv,
                                          int rowTile, int colTile) {
    constexpr int K = DMODEL, N = DMODEL;
    __shared__ f16 As[128 * 64];
    __shared__ f16 Bs[128 * 64];
    const int t = threadIdx.x;
    const int lane = t & 63;
    const int w = t >> 6;
    const int wm = w >> 1, wn = w & 1;
    const long rowBase = (long)rowTile * 128;
    const long colBase = (long)colTile * 128;
    const int qrow = lane & 15;
    const int quad = lane >> 4;

    v4f acc[4][4] = {};

    // staging: thread t covers rows srow+32i (i=0..3), LDS chunk schunk holds
    // global chunk schunk^(srow&7)  (i*32 = 0 mod 8 -> same xor)
    const int srow = t >> 3;          // 0..31
    const int schunk = t & 7;
    const int gchunk = schunk ^ (srow & 7);
    const f16* aptr = A + (rowBase + srow) * (long)K + gchunk * 8;
    const f16* bptr = Bt + (colBase + srow) * (long)K + gchunk * 8;
    f16* lA = &As[srow * 64 + schunk * 8];
    f16* lB = &Bs[srow * 64 + schunk * 8];

    for (int k0 = 0; k0 < K; k0 += 64) {
#pragma unroll
        for (int i = 0; i < 4; ++i) {
            async_copy16(aptr + k0 + i * 32 * (long)K, lA + i * 2048);
            async_copy16(bptr + k0 + i * 32 * (long)K, lB + i * 2048);
        }
        __syncthreads();  // drains vmcnt(0): staged tile visible
#pragma unroll
        for (int s = 0; s < 2; ++s) {   // two K=32 MFMA steps per BK=64 tile
            const int xk = (s * 4 + quad) ^ (qrow & 7);  // swizzled chunk
            f16x8 af[4], bf[4];
#pragma unroll
            for (int mt = 0; mt < 4; ++mt)
                af[mt] = *(const f16x8*)(&As[(wm * 64 + mt * 16 + qrow) * 64 + xk * 8]);
#pragma unroll
            for (int nt = 0; nt < 4; ++nt)
                bf[nt] = *(const f16x8*)(&Bs[(wn * 64 + nt * 16 + qrow) * 64 + xk * 8]);
#pragma unroll
            for (int mt = 0; mt < 4; ++mt)
#pragma unroll
                for (int nt = 0; nt < 4; ++nt)
                    acc[mt][nt] = __builtin_amdgcn_mfma_f32_16x16x32_f16(
                        af[mt], bf[nt], acc[mt][nt], 0, 0, 0);
        }
        __syncthreads();  // all reads done before next stage overwrites
    }

    // C/D layout (m89-verified): row = quad*4 + r, col = lane&15
#pragma unroll
    for (int mt = 0; mt < 4; ++mt)
#pragma unroll
        for (int nt = 0; nt < 4; ++nt) {
            const long col = colBase + wn * 64 + nt * 16 + qrow;
#pragma unroll
            for (int r = 0; r < 4; ++r) {
                const long row = rowBase + wm * 64 + mt * 16 + quad * 4 + r;
                if (OUT_F32)
                    ((float*)Cv)[row * (long)N + col] = acc[mt][nt][r];
                else
                    ((f16*)Cv)[row * (long)N + col] = (f16)acc[mt][nt][r];
            }
        }
}

// Fused Q/K/V projection, 1024 blocks, XCD-swizzled (R4-verified: FETCH -82%).
__global__ __launch_bounds__(256, 2)
void gemm_qkv(const f16* __restrict__ A0, const f16* __restrict__ A1,
              const f16* __restrict__ A2, const f16* __restrict__ B0,
              const f16* __restrict__ B1, const f16* __restrict__ B2,
              f16* __restrict__ C0, f16* __restrict__ C1, f16* __restrict__ C2) {
    const int id = blockIdx.x;
    const int xcd = id & 7;
    const int g = id >> 3;            // 0..127
    const int ct = g & 7;             // col tile
    int rowIdx = (g >> 3) + xcd * 16; // 0..127
    const f16 *A, *Bt;
    f16* C;
    if (rowIdx < 64) {
        A = A0; Bt = B0; C = C0;
    } else if (rowIdx < 96) {
        A = A1; Bt = B1; C = C1; rowIdx -= 64;
    } else {
        A = A2; Bt = B2; C = C2; rowIdx -= 96;
    }
    gemm_body<false>(A, Bt, (void*)C, rowIdx, ct);
}

__global__ __launch_bounds__(256, 2)
void gemm_out(const f16* __restrict__ A, const f16* __restrict__ Bt,
              float* __restrict__ C) {
    const int id = blockIdx.x;        // 512 blocks
    const int xcd = id & 7;
    const int g = id >> 3;            // 0..63
    const int ct = g & 7;
    const int rowIdx = (g >> 3) + xcd * 8;  // 0..63
    gemm_body<true>(A, Bt, (void*)C, rowIdx, ct);
}

// -------- per-column scores + softmax over the 16 valid query rows ----------
__global__ __launch_bounds__(256)
void attn_scores(const f16* __restrict__ Q, const f16* __restrict__ Km,
                 float* __restrict__ attnw) {
    const int c0 = blockIdx.x * 4, b = blockIdx.y;
    const int t = threadIdx.x;
    __shared__ f16 Qs[24 * 1032];   // rows 0..21 used; 49.5 KB
    __shared__ f16 Ks[4 * 1032];    // 8.25 KB

#pragma unroll
    for (int it = 0; it < 12; ++it) {
        const int ch = t + 256 * it;        // 24 rows x 128 chunks
        const int row = ch >> 7, off = (ch & 127) * 8;
        int qq = 2 * c0 + row;
        if (qq > LQ_ - 1) qq = LQ_ - 1;     // clamp staging; masked in score
        f16x8 x = *(const f16x8*)(Q + (size_t)(b * LQ_ + qq) * DMODEL + off);
        const int h = off >> 6, bb = (off >> 3) & 7;
        *(f16x8*)(&Qs[row * 1032 + h * 64 + ((bb + h) & 7) * 8]) = x;
    }
#pragma unroll
    for (int it = 0; it < 2; ++it) {
        const int ch = t + 256 * it;        // 4 rows x 128 chunks
        const int row = ch >> 7, off = (ch & 127) * 8;
        f16x8 x = *(const f16x8*)(Km + (size_t)(b * LKV_ + c0 + row) * DMODEL + off);
        const int h = off >> 6, bb = (off >> 3) & 7;
        *(f16x8*)(&Ks[row * 1032 + h * 64 + ((bb + h) & 7) * 8]) = x;
    }
    __syncthreads();

    const int h = t >> 4, j = t & 15;
#pragma unroll
    for (int ci = 0; ci < 4; ++ci) {
        const int c = c0 + ci;
        const int q = STRIDE * c + j;
        const int row = 2 * ci + j;
        float a = 0.f;
#pragma unroll
        for (int bb = 0; bb < 8; ++bb) {
            const int off = h * 64 + ((bb + h) & 7) * 8;
            f16x8 qv = *(const f16x8*)(&Qs[row * 1032 + off]);
            f16x8 kv = *(const f16x8*)(&Ks[ci * 1032 + off]);  // wave-broadcast
#pragma unroll
            for (int u = 0; u < 8; ++u) a += (float)qv[u] * (float)kv[u];
        }
        float s = (q < LQ_) ? a : -1e30f;
        float m = s;
#pragma unroll
        for (int o = 1; o < 16; o <<= 1) m = fmaxf(m, __shfl_xor(m, o, 64));
        float p = (q < LQ_) ? __expf(s - m) : 0.f;
        float sum = p;
#pragma unroll
        for (int o = 1; o < 16; o <<= 1) sum += __shfl_xor(sum, o, 64);
        attnw[(size_t)((b * LKV_ + c) * NH + h) * SPAN + j] = p / sum;
    }
}

// ---- ctx[b,q,h,:] = sum_i attn[b, q/2-i, h, (q&1)+2i] * V[b, q/2-i, h, :] ----
__global__ __launch_bounds__(256)
void ctx_gather(const float* __restrict__ attnw, const f16* __restrict__ V,
                f16* __restrict__ ctx) {
    const int q0 = blockIdx.x * 16, b = blockIdx.y;
    const int t = threadIdx.x;
    const int kbase = (q0 >> 1) - 7;
    __shared__ f16 Vs[16 * 1024];     // 32 KB
    __shared__ float A_lds[16 * 256]; // 16 KB

#pragma unroll
    for (int it = 0; it < 8; ++it) {
        const int ch = t + 256 * it;       // 16 rows x 128 chunks
        const int row = ch >> 7, off = (ch & 127) * 8;
        int k = kbase + row;
        k = (k < 0) ? 0 : ((k > LKV_ - 1) ? LKV_ - 1 : k);
        *(f16x8*)(&Vs[row * 1024 + off]) =
            *(const f16x8*)(V + (size_t)(b * LKV_ + k) * DMODEL + off);
    }
#pragma unroll
    for (int it = 0; it < 4; ++it) {
        const int ch = t + 256 * it;       // 16 rows x 64 chunks of 4 f32
        const int row = ch >> 6, off = (ch & 63) * 4;
        int k = kbase + row;
        k = (k < 0) ? 0 : ((k > LKV_ - 1) ? LKV_ - 1 : k);
        *(float4*)(&A_lds[row * 256 + off]) =
            *(const float4*)(attnw + (size_t)(b * LKV_ + k) * 256 + off);
    }
    __syncthreads();

    const int d = t & 63;
    const int hg = t >> 6;
#pragma unroll
    for (int ql = 0; ql < 16; ++ql) {
        const int q = q0 + ql;
        const int j0 = q & 1;
        float acc[4] = {0.f, 0.f, 0.f, 0.f};
#pragma unroll
        for (int i = 0; i < SPAN / STRIDE; ++i) {
            const int kq = (q >> 1) - i;
            if (kq < 0) break;
            const int rr = kq - kbase;
#pragma unroll
            for (int hh = 0; hh < 4; ++hh) {
                const int h = hg * 4 + hh;
                acc[hh] += A_lds[rr * 256 + h * 16 + j0 + 2 * i] *
                           (float)Vs[rr * 1024 + h * 64 + d];
            }
        }
        f16* crow = ctx + (size_t)(b * LQ_ + q) * DMODEL;
#pragma unroll
        for (int hh = 0; hh < 4; ++hh) {
            const int h = hg * 4 + hh;
            crow[h * HD + d] = (f16)acc[hh];
        }
    }
}

// ---------------------------------------------------------------------------
extern "C" void kernel_launch(void* const* d_in, const int* in_sizes, int n_in,
                              void* d_out, int out_size, void* d_ws, size_t ws_size,
                              hipStream_t stream) {
    const float* q  = (const float*)d_in[0];
    const float* k  = (const float*)d_in[1];
    const float* v  = (const float*)d_in[2];
    const float* Wq = (const float*)d_in[3];
    const float* Wk = (const float*)d_in[4];
    const float* Wv = (const float*)d_in[5];
    const float* Wo = (const float*)d_in[6];
    float* out = (float*)d_out;

    const size_t NW = (size_t)DMODEL * DMODEL;

    char* p = (char*)d_ws;
    f16* qh  = (f16*)p; p += NQ_ELEMS * 2;
    f16* kh  = (f16*)p; p += NKV_ELEMS * 2;
    f16* vh  = (f16*)p; p += NKV_ELEMS * 2;
    f16* WqT = (f16*)p; p += NW * 2;
    f16* WkT = (f16*)p; p += NW * 2;
    f16* WvT = (f16*)p; p += NW * 2;
    f16* WoT = (f16*)p; p += NW * 2;
    f16* Qh  = (f16*)p; p += NQ_ELEMS * 2;
    f16* Kh  = (f16*)p; p += NKV_ELEMS * 2;
    f16* Vh  = (f16*)p; p += NKV_ELEMS * 2;
    float* attnw = (float*)p; p += (size_t)B_ * LKV_ * NH * SPAN * 4;
    f16* ctxh = (f16*)p; p += NQ_ELEMS * 2;

    // 1) fused converts (8 elems/thread) + weight transposes
    prep_all<<<dim3(9216), 256, 0, stream>>>(q, k, v, qh, kh, vh,
                                             Wq, Wk, Wv, Wo, WqT, WkT, WvT, WoT);

    // 2) Q/K/V projections fused, XCD-swizzled, all-f16 global_load_lds
    gemm_qkv<<<dim3(1024), 256, 0, stream>>>(qh, kh, vh, WqT, WkT, WvT, Qh, Kh, Vh);

    // 3) per-column masked scores + query-axis softmax
    attn_scores<<<dim3(LKV_ / 4, B_), 256, 0, stream>>>(Qh, Kh, attnw);

    // 4) per-query gather of weighted V
    ctx_gather<<<dim3(LQ_ / 16, B_), 256, 0, stream>>>(attnw, Vh, ctxh);

    // 5) output projection (f32 out), XCD-swizzled
    gemm_out<<<dim3(512), 256, 0, stream>>>(ctxh, WoT, out);
}